// Round 1
// baseline (338.546 us; speedup 1.0000x reference)
//
#include <hip/hip_runtime.h>

#define NB 32
#define NS 2048
#define ND 512
#define NA 64
#define NE 64

typedef __bf16 bf16x8 __attribute__((ext_vector_type(8)));
typedef float f32x4 __attribute__((ext_vector_type(4)));

__device__ __forceinline__ unsigned short f2bf(float f) {
    union { float f; unsigned u; } v; v.f = f;
    unsigned r = (v.u + 0x7fffu + ((v.u >> 16) & 1u)) >> 16;
    return (unsigned short)r;
}
__device__ __forceinline__ unsigned pk(float a, float b) {
    return (unsigned)f2bf(a) | ((unsigned)f2bf(b) << 16);
}

// ---------------------------------------------------------------------------
// Kernel 1b (runs FIRST): the six small per-sample vectors, per b:
// [pre_w 512][pre_b 512][post_w 512][post_b 512][b_up 512][b_down 64] = 2624
// ---------------------------------------------------------------------------
__global__ __launch_bounds__(256) void hyper_vec(
    const float* __restrict__ emb,
    const float* __restrict__ pwW, const float* __restrict__ pwb,
    const float* __restrict__ pbW, const float* __restrict__ pbb,
    const float* __restrict__ powW, const float* __restrict__ powb,
    const float* __restrict__ pobW, const float* __restrict__ pobb,
    const float* __restrict__ ubW, const float* __restrict__ ubb,
    const float* __restrict__ dbW, const float* __restrict__ dbb,
    float* __restrict__ vecs) {
    int gid = blockIdx.x * 256 + threadIdx.x;
    if (gid >= NB * 2624) return;
    int b = gid / 2624;
    int r = gid - b * 2624;
    const float* W; const float* bias; int off, width;
    if (r < 2560) {
        int v = r >> 9; off = r & 511; width = 512;
        switch (v) {
            case 0:  W = pwW;  bias = pwb;  break;
            case 1:  W = pbW;  bias = pbb;  break;
            case 2:  W = powW; bias = powb; break;
            case 3:  W = pobW; bias = pobb; break;
            default: W = ubW;  bias = ubb;  break;
        }
    } else {
        off = r - 2560; width = 64; W = dbW; bias = dbb;
    }
    float acc = bias[off];
    const float* e = emb + b * 64;
#pragma unroll 8
    for (int k = 0; k < 64; ++k) acc = fmaf(e[k], W[k * width + off], acc);
    vecs[gid] = acc;
}

// ---------------------------------------------------------------------------
// Kernel 1a: hypernet big GEMMs emb[32,64] @ W[64,32768] -> bf16 frags.
// mat==0 (down): fold pre-LN weight in-line (f = raw*pre_w), emit folded
//   frags [b][nt(4)][kc(16)][lane(64)][8] and atomically accumulate
//   c1[b,a]=sum_d raw*pre_b, c2[b,a]=sum_d raw*pre_w into cvec[b][a][2].
// mat==1 (up): frags [b][nblk(32)][kch(2)][lane(64)][8].
// ---------------------------------------------------------------------------
__global__ __launch_bounds__(256) void hyper_pack(
    const float* __restrict__ emb,
    const float* __restrict__ dwW, const float* __restrict__ dwb,
    const float* __restrict__ uwW, const float* __restrict__ uwb,
    const float* __restrict__ vecs,
    unsigned short* __restrict__ wdfrag, unsigned short* __restrict__ wufrag,
    float* __restrict__ cvec) {
    __shared__ float Wt[64][128];
    __shared__ float embs[NB * NE];
    const int tid = threadIdx.x;
    const int lane = tid & 63;
    const int bx = blockIdx.x;
    const int mat = bx >> 8;
    const int chunk = bx & 255;
    const int base = chunk * 128;
    const int colo = tid & 127;
    const int bh = tid >> 7;            // 0 or 1: b-range [16*bh, 16*bh+16)
    const float* W = mat ? uwW : dwW;
    const float* bias = mat ? uwb : dwb;

    for (int i = tid; i < NB * NE; i += 256) embs[i] = emb[i];
    for (int i = tid; i < 64 * 32; i += 256) {
        int k = i >> 5, c = (i & 31) << 2;
        *(float4*)&Wt[k][c] = *(const float4*)&W[(size_t)k * 32768 + base + c];
    }
    __syncthreads();

    const int col = base + colo;
    const float bv = bias[col];
    float acc[16];
#pragma unroll
    for (int b = 0; b < 16; ++b) acc[b] = bv;

    for (int k0 = 0; k0 < 64; k0 += 4) {
        float w0 = Wt[k0][colo], w1 = Wt[k0 + 1][colo];
        float w2 = Wt[k0 + 2][colo], w3 = Wt[k0 + 3][colo];
#pragma unroll
        for (int b = 0; b < 16; ++b) {
            float4 e = *(const float4*)&embs[(bh * 16 + b) * 64 + k0];
            acc[b] = fmaf(e.x, w0, acc[b]);
            acc[b] = fmaf(e.y, w1, acc[b]);
            acc[b] = fmaf(e.z, w2, acc[b]);
            acc[b] = fmaf(e.w, w3, acc[b]);
        }
    }

    if (mat == 0) {
        int a = col >> 9, d = col & 511;   // a uniform per block (128 | 512)
        size_t idx0 = ((size_t)((a >> 4) * 16 + (d >> 5)) * 64 +
                       (((d & 31) >> 3) * 16 + (a & 15))) * 8 + (d & 7);
#pragma unroll
        for (int b = 0; b < 16; ++b) {
            int bg = bh * 16 + b;
            float raw = acc[b];
            float pw = vecs[bg * 2624 + d];
            float pb = vecs[bg * 2624 + 512 + d];
            float f = raw * pw;
            wdfrag[idx0 + (size_t)bg * 32768] = f2bf(f);
            float c2v = f, c1v = raw * pb;
#pragma unroll
            for (int m = 1; m <= 32; m <<= 1) {
                c2v += __shfl_xor(c2v, m);
                c1v += __shfl_xor(c1v, m);
            }
            if (lane == 0) {
                atomicAdd(&cvec[bg * 128 + 2 * a], c1v);
                atomicAdd(&cvec[bg * 128 + 2 * a + 1], c2v);
            }
        }
    } else {
        int d = col >> 6, a = col & 63;
        size_t idx0 = ((size_t)((d >> 4) * 2 + (a >> 5)) * 64 +
                       (((a & 31) >> 3) * 16 + (d & 15))) * 8 + (a & 7);
#pragma unroll
        for (int b = 0; b < 16; ++b)
            wufrag[idx0 + (size_t)(bh * 16 + b) * 32768] = f2bf(acc[b]);
    }
}

// ---------------------------------------------------------------------------
// Kernel 2: fused [foldedLN + down MFMA] -> relu -> up (MFMA, col-split) ->
// postLN -> +x.  4096 blocks x 256 threads; block = (b, 16-row S-tile).
//
// Restructured (register-z): each wave keeps its K-quarter of x in registers
// (the loaded bf16 packs ARE the 16x16x32 A-fragments) and computes a partial
// down-product over that quarter for ALL 4 nt (16 MFMAs, 4 indep acc chains).
// The 4 wave-partials are reduced through a small f32 LDS buffer in the
// finalize step (pre-LN fold is linear, so partial-sum-then-affine is exact).
// This removes z_lds (and its bank-conflicting stores), removes the
// load->barrier->dependent-weight-load serialization (input HBM loads, wd L2
// loads, stats and MFMAs all live in one barrier-free region), and shortens
// MFMA dependency chains 16 -> 4.
// ---------------------------------------------------------------------------
__global__ __launch_bounds__(256, 4) void fused_adapter(
    const float* __restrict__ inp,
    const unsigned short* __restrict__ wdfold,
    const unsigned short* __restrict__ wufrag,
    const float* __restrict__ vecs,
    const float* __restrict__ cvec,
    float* __restrict__ out) {
    __shared__ __align__(16) float p_lds[4][16][68];       // wave partials (+pad)
    __shared__ __align__(16) unsigned short mid_lds[16][72];
    __shared__ __align__(16) float coeff[1536];  // post_w | post_b | b_up
    __shared__ __align__(16) float preS[16][4], preQ[16][4];
    __shared__ __align__(16) float postS[16][4], postQ[16][4];

    const int tid = threadIdx.x;
    const int lane = tid & 63;
    const int wave = tid >> 6;
    const int lanelo = lane & 15;
    const int quad = lane >> 4;
    // bijective XCD swizzle: all 128 blocks of one b land on one XCD's L2,
    // so the 128 KB of adapter weights are XCD-resident (512 KB/XCD vs 4 MB).
    const int bx0 = blockIdx.x;
    const int bx = (bx0 & 7) * 512 + (bx0 >> 3);
    const int b = bx >> 7;
    const int s0 = (bx & 127) * 16;

    const float* vb = vecs + b * 2624;

    // ---- Phase A: issue the 8 HBM input loads first (longest latency) ----
    const float* xp = inp + ((size_t)b * NS + s0 + lanelo) * ND + wave * 128 + quad * 8;
    float4 x0[4], x1[4];
#pragma unroll
    for (int kc2 = 0; kc2 < 4; ++kc2) {
        x0[kc2] = *(const float4*)(xp + kc2 * 32);
        x1[kc2] = *(const float4*)(xp + kc2 * 32 + 4);
    }

    for (int i = tid; i < 384; i += 256)
        ((float4*)coeff)[i] = ((const float4*)(vb + 1024))[i];

    // stats + pack bf16 A-fragments (registers, no LDS round-trip)
    uint4 au[4];
    float s = 0.f, q = 0.f;
#pragma unroll
    for (int kc2 = 0; kc2 < 4; ++kc2) {
        float4 a = x0[kc2], c = x1[kc2];
        s += (a.x + a.y + a.z + a.w) + (c.x + c.y + c.z + c.w);
        q = fmaf(a.x, a.x, q); q = fmaf(a.y, a.y, q);
        q = fmaf(a.z, a.z, q); q = fmaf(a.w, a.w, q);
        q = fmaf(c.x, c.x, q); q = fmaf(c.y, c.y, q);
        q = fmaf(c.z, c.z, q); q = fmaf(c.w, c.w, q);
        au[kc2].x = pk(a.x, a.y); au[kc2].y = pk(a.z, a.w);
        au[kc2].z = pk(c.x, c.y); au[kc2].w = pk(c.z, c.w);
    }
    s += __shfl_xor(s, 16); s += __shfl_xor(s, 32);
    q += __shfl_xor(q, 16); q += __shfl_xor(q, 32);
    if (lane < 16) { preS[lane][wave] = s; preQ[lane][wave] = q; }

    // ---- Phase B: down partial GEMM over this wave's K-quarter, all 4 nt ----
    const unsigned short* wd = wdfold + (size_t)b * 32768;
    const unsigned short* wdp = wd + ((size_t)(wave * 4) * 64 + lane) * 8;
    f32x4 acc[4];
#pragma unroll
    for (int nt = 0; nt < 4; ++nt) acc[nt] = (f32x4){0.f, 0.f, 0.f, 0.f};
#pragma unroll
    for (int kc2 = 0; kc2 < 4; ++kc2) {
        bf16x8 af = __builtin_bit_cast(bf16x8, au[kc2]);
#pragma unroll
        for (int nt = 0; nt < 4; ++nt) {
            uint4 bu = *(const uint4*)(wdp + (size_t)(nt * 16 + kc2) * 512);
            acc[nt] = __builtin_amdgcn_mfma_f32_16x16x32_bf16(
                af, __builtin_bit_cast(bf16x8, bu), acc[nt], 0, 0, 0);
        }
    }
    // write wave partials: C-frag (row = quad*4+r, a = nt*16+lanelo)
#pragma unroll
    for (int nt = 0; nt < 4; ++nt)
#pragma unroll
        for (int r = 0; r < 4; ++r)
            p_lds[wave][quad * 4 + r][nt * 16 + lanelo] = acc[nt][r];
    __syncthreads();  // partials + pre-stats + coeff visible

    // ---- finalize mid: 4-way partial sum + folded pre-LN affine + relu ----
    {
        const int row = tid >> 4;
        const int a0 = (tid & 15) << 2;
        float4 S = *(const float4*)preS[row];
        float4 Q = *(const float4*)preQ[row];
        float ss = (S.x + S.y) + (S.z + S.w);
        float qq = (Q.x + Q.y) + (Q.z + Q.w);
        float mean = ss * (1.0f / 512.0f);
        float var = qq * (1.0f / 512.0f) - mean * mean;
        float rstd = rsqrtf(var + 1e-5f);
        float mrs = mean * rstd;
        f32x4 v = *(const f32x4*)&p_lds[0][row][a0];
        v = v + *(const f32x4*)&p_lds[1][row][a0];
        v = v + *(const f32x4*)&p_lds[2][row][a0];
        v = v + *(const f32x4*)&p_lds[3][row][a0];
        float4 cv0 = *(const float4*)&cvec[b * 128 + 2 * a0];
        float4 cv1 = *(const float4*)&cvec[b * 128 + 2 * a0 + 4];
        float4 bd = *(const float4*)&vb[2560 + a0];
        ushort4 m;
        m.x = f2bf(fmaxf(fmaf(rstd, v[0], fmaf(-mrs, cv0.y, cv0.x + bd.x)), 0.f));
        m.y = f2bf(fmaxf(fmaf(rstd, v[1], fmaf(-mrs, cv0.w, cv0.z + bd.y)), 0.f));
        m.z = f2bf(fmaxf(fmaf(rstd, v[2], fmaf(-mrs, cv1.y, cv1.x + bd.z)), 0.f));
        m.w = f2bf(fmaxf(fmaf(rstd, v[3], fmaf(-mrs, cv1.w, cv1.z + bd.w)), 0.f));
        *(ushort4*)&mid_lds[row][a0] = m;
    }
    __syncthreads();  // mid visible

    // ---- Phase C: up GEMM, wave w -> cols [128w,128w+128), acc[8] ----
    uint4 a0u = *(const uint4*)&mid_lds[lanelo][quad * 8];
    uint4 a1u = *(const uint4*)&mid_lds[lanelo][32 + quad * 8];
    bf16x8 af0 = __builtin_bit_cast(bf16x8, a0u);
    bf16x8 af1 = __builtin_bit_cast(bf16x8, a1u);
    const unsigned short* wu = wufrag + (size_t)b * 32768;
    f32x4 acc8[8];
    float sum[4] = {0.f, 0.f, 0.f, 0.f}, sq[4] = {0.f, 0.f, 0.f, 0.f};
#pragma unroll
    for (int nt8 = 0; nt8 < 8; ++nt8) {
        int nt = wave * 8 + nt8;
        uint4 b0 = *(const uint4*)(wu + ((size_t)(nt * 2 + 0) * 64 + lane) * 8);
        uint4 b1 = *(const uint4*)(wu + ((size_t)(nt * 2 + 1) * 64 + lane) * 8);
        f32x4 a4 = (f32x4){0.f, 0.f, 0.f, 0.f};
        a4 = __builtin_amdgcn_mfma_f32_16x16x32_bf16(af0, __builtin_bit_cast(bf16x8, b0), a4, 0, 0, 0);
        a4 = __builtin_amdgcn_mfma_f32_16x16x32_bf16(af1, __builtin_bit_cast(bf16x8, b1), a4, 0, 0, 0);
        float bu = coeff[1024 + nt * 16 + lanelo];
#pragma unroll
        for (int r = 0; r < 4; ++r) {
            float y = a4[r] + bu;
            a4[r] = y;
            sum[r] += y;
            sq[r] = fmaf(y, y, sq[r]);
        }
        acc8[nt8] = a4;
    }
#pragma unroll
    for (int r = 0; r < 4; ++r) {
#pragma unroll
        for (int m = 1; m <= 8; m <<= 1) {
            sum[r] += __shfl_xor(sum[r], m);
            sq[r] += __shfl_xor(sq[r], m);
        }
    }
    if (lanelo == 0) {
#pragma unroll
        for (int r = 0; r < 4; ++r) {
            postS[quad * 4 + r][wave] = sum[r];
            postQ[quad * 4 + r][wave] = sq[r];
        }
    }
    __syncthreads();  // post-stat partials visible

    float mean2[4], rstd2[4];
#pragma unroll
    for (int r = 0; r < 4; ++r) {
        int row = quad * 4 + r;
        float4 S = *(const float4*)postS[row];
        float4 Q = *(const float4*)postQ[row];
        float ss = (S.x + S.y) + (S.z + S.w);
        float qq = (Q.x + Q.y) + (Q.z + Q.w);
        mean2[r] = ss * (1.0f / 512.0f);
        float v2 = qq * (1.0f / 512.0f) - mean2[r] * mean2[r];
        rstd2[r] = rsqrtf(v2 + 1e-5f);
    }

    // ---- epilogue: post-LN affine, +x, store ----
    const size_t obase = ((size_t)b * NS + s0) * ND;
#pragma unroll
    for (int nt8 = 0; nt8 < 8; ++nt8) {
        int col = (wave * 8 + nt8) * 16 + lanelo;
        float pw = coeff[col];
        float pb = coeff[512 + col];
#pragma unroll
        for (int r = 0; r < 4; ++r) {
            size_t off = obase + (size_t)(quad * 4 + r) * ND + col;
            out[off] = fmaf((acc8[nt8][r] - mean2[r]) * rstd2[r], pw, pb) + inp[off];
        }
    }
}

// ---------------------------------------------------------------------------
extern "C" void kernel_launch(void* const* d_in, const int* in_sizes, int n_in,
                              void* d_out, int out_size, void* d_ws, size_t ws_size,
                              hipStream_t stream) {
    const float* emb  = (const float*)d_in[0];
    const float* inp  = (const float*)d_in[1];
    const float* dwW  = (const float*)d_in[2];
    const float* dwb  = (const float*)d_in[3];
    const float* dbW  = (const float*)d_in[4];
    const float* dbb  = (const float*)d_in[5];
    const float* uwW  = (const float*)d_in[6];
    const float* uwb  = (const float*)d_in[7];
    const float* ubW  = (const float*)d_in[8];
    const float* ubb  = (const float*)d_in[9];
    const float* pwW  = (const float*)d_in[10];
    const float* pwb  = (const float*)d_in[11];
    const float* pbW  = (const float*)d_in[12];
    const float* pbb  = (const float*)d_in[13];
    const float* powW = (const float*)d_in[14];
    const float* powb = (const float*)d_in[15];
    const float* pobW = (const float*)d_in[16];
    const float* pobb = (const float*)d_in[17];

    unsigned short* wdfrag = (unsigned short*)d_ws;
    unsigned short* wufrag = wdfrag + (size_t)NB * 32768;
    float* vecs = (float*)(wufrag + (size_t)NB * 32768);
    float* cvec = vecs + (size_t)NB * 2624;

    hyper_vec<<<(NB * 2624 + 255) / 256, 256, 0, stream>>>(
        emb, pwW, pwb, pbW, pbb, powW, powb, pobW, pobb, ubW, ubb, dbW, dbb, vecs);
    hipMemsetAsync(cvec, 0, (size_t)NB * 128 * sizeof(float), stream);
    hyper_pack<<<512, 256, 0, stream>>>(emb, dwW, dwb, uwW, uwb, vecs,
                                        wdfrag, wufrag, cvec);
    fused_adapter<<<NB * (NS / 16), 256, 0, stream>>>(
        inp, wdfrag, wufrag, vecs, cvec, (float*)d_out);
}